// Round 3
// baseline (223.139 us; speedup 1.0000x reference)
//
#include <hip/hip_runtime.h>

typedef __attribute__((ext_vector_type(2))) float f32x2;
typedef __attribute__((ext_vector_type(4))) float f32x4;
typedef __attribute__((ext_vector_type(8))) short s16x8;
typedef __attribute__((ext_vector_type(2))) unsigned int u32x2;
typedef __attribute__((ext_vector_type(4))) unsigned int u32x4;

#define BN 4
#define TN 4096
#define CN 120
#define HN 64

// RNE float->bf16 (finite inputs only)
__device__ __forceinline__ unsigned short f2bf(float f) {
  unsigned int u = __float_as_uint(f);
  unsigned int r = (u + 0x7fffu + ((u >> 16) & 1u)) >> 16;
  return (unsigned short)r;
}

__device__ __forceinline__ float fast_exp2(float x) {
#if __has_builtin(__builtin_amdgcn_exp2f)
  return __builtin_amdgcn_exp2f(x);
#else
  return exp2f(x);
#endif
}

// ---------------------------------------------------------------------------
// Kernel 1: projections. 16 rows/block (grid 1024 -> 4 blocks/CU, 16 waves/CU
// for latency hiding; round-1's 64-row version ran at 1 block/CU and was
// ~87us of exposed W-load latency). Each thread: 2 rows x 2 h-columns x 3 mats.
//   Kg [b*T+t][64]  bf16 rows
//   Qg [b*T+t][64]  bf16 rows, pre-scaled by log2(e)/sqrt(C)
//   Vt [b][h][t]    bf16 transposed for attention's PV A-operand
// ---------------------------------------------------------------------------
__global__ __launch_bounds__(256) void proj_kernel(
    const float* __restrict__ x, const float* __restrict__ Wk,
    const float* __restrict__ Wq, const float* __restrict__ Wv,
    unsigned short* __restrict__ Kg, unsigned short* __restrict__ Qg,
    unsigned short* __restrict__ Vt) {
  __shared__ union {
    float xl[16 * CN];            // 7680 B
    unsigned short vt[64 * 24];   // 3072 B (pitch 24 keeps 16B read align)
  } sm;
  const int tid = threadIdx.x;
  const int row0 = blockIdx.x * 16;
  {
    const f32x4* xs = (const f32x4*)(x + (size_t)row0 * CN);
    f32x4* xd = (f32x4*)sm.xl;
    for (int i = tid; i < 16 * CN / 4; i += 256) xd[i] = xs[i];
  }
  __syncthreads();
  const int hp = tid & 31;  // h pair: h = 2hp, 2hp+1
  const int rg = tid >> 5;  // rows 2rg, 2rg+1
  f32x2 aK[2], aQ[2], aV[2];
#pragma unroll
  for (int r = 0; r < 2; ++r) { aK[r] = 0.f; aQ[r] = 0.f; aV[r] = 0.f; }
  for (int c = 0; c < CN; c += 4) {
    f32x4 xv[2];
#pragma unroll
    for (int r = 0; r < 2; ++r)
      xv[r] = *(const f32x4*)&sm.xl[(rg * 2 + r) * CN + c];
#pragma unroll
    for (int cc = 0; cc < 4; ++cc) {
      const f32x2 wk = *(const f32x2*)&Wk[(c + cc) * HN + 2 * hp];
      const f32x2 wq = *(const f32x2*)&Wq[(c + cc) * HN + 2 * hp];
      const f32x2 wv = *(const f32x2*)&Wv[(c + cc) * HN + 2 * hp];
#pragma unroll
      for (int r = 0; r < 2; ++r) {
        const float xx = xv[r][cc];
        aK[r] += wk * xx;
        aQ[r] += wq * xx;
        aV[r] += wv * xx;
      }
    }
  }
  const float QSC = 0.131720936f;  // log2(e)/sqrt(120)
#pragma unroll
  for (int r = 0; r < 2; ++r) {
    const int row = rg * 2 + r;
    const size_t idx = (size_t)(row0 + row) * HN + 2 * hp;
    const unsigned int kp =
        (unsigned int)f2bf(aK[r][0]) | ((unsigned int)f2bf(aK[r][1]) << 16);
    const unsigned int qp = (unsigned int)f2bf(aQ[r][0] * QSC) |
                            ((unsigned int)f2bf(aQ[r][1] * QSC) << 16);
    *(unsigned int*)&Kg[idx] = kp;
    *(unsigned int*)&Qg[idx] = qp;
  }
  // V transpose through LDS, then global write of Vt row chunks
  __syncthreads();
#pragma unroll
  for (int r = 0; r < 2; ++r) {
    const int row = rg * 2 + r;
    sm.vt[(2 * hp) * 24 + row] = f2bf(aV[r][0]);
    sm.vt[(2 * hp + 1) * 24 + row] = f2bf(aV[r][1]);
  }
  __syncthreads();
  if (tid < 128) {
    const int h = tid >> 1, ck = tid & 1;
    const int b = row0 >> 12, key0 = row0 & (TN - 1);
    const u32x4 d = *(const u32x4*)&sm.vt[h * 24 + ck * 8];
    *(u32x4*)(Vt + (size_t)(b * HN + h) * TN + key0 + ck * 8) = d;
  }
}

// ---------------------------------------------------------------------------
// Kernel 2: attention. One block = 16 queries; 4 waves each own a disjoint
// 1024-key range. Software-pipelined 64-key steps:
//   S-MFMAs consume K frags loaded LAST iteration (full-iter latency cover);
//   next-iter K loads + this-iter V loads issue before the ~200cy exp2/pack
//   stretch, so PV's s_waitcnt on V is free. Only exposed hop: LDS P
//   transpose write->read.
// No online max: logits are pre-scaled by log2(e)/sqrt(120), bounded ~+-6,
// exp2 can't overflow (clamped at 80), so key-split partials (O,l) merge by
// plain summation in the epilogue.
// ---------------------------------------------------------------------------
__global__ __launch_bounds__(256, 4) void attn_kernel(
    const unsigned short* __restrict__ Qg, const unsigned short* __restrict__ Kg,
    const unsigned short* __restrict__ Vt, float* __restrict__ out) {
  __shared__ union {
    unsigned short p[4][16][72];                  // 9216 B, wave-private rows
    struct { float ob[4][64][17]; float lb[4][16]; } m;  // epilogue merge
  } sm;
  const int bid = blockIdx.x;
  const int xslot = bid & 7;                 // XCD-aware swizzle:
  const int b = xslot >> 1;                  // batch pinned to an XCD pair so
  const int qt = (bid >> 3) | ((xslot & 1) << 7);  // K+Vt (1MB) stays L2-hot
  const int qbase = qt * 16;
  const int tid = threadIdx.x;
  const int wave = tid >> 6, lane = tid & 63;
  const int l15 = lane & 15, quad = lane >> 4;

  // Q B-operand frags: B[k=h][n=q]: q = lane&15, h = quad*8+j (+32)
  const unsigned short* qrow =
      Qg + (size_t)(b * TN + qbase + l15) * HN + quad * 8;
  const s16x8 qf0 = *(const s16x8*)qrow;
  const s16x8 qf1 = *(const s16x8*)(qrow + 32);

  const unsigned short* Kb = Kg + (size_t)b * TN * HN;
  const unsigned short* Vb = Vt + (size_t)b * HN * TN;
  char* const pw = (char*)&sm.p[wave][0][0] + l15 * 144;  // write row q=l15
  char* const pr = (char*)&sm.p[wave][0][0] + l15 * 144 + quad * 16;

  const int kb0 = wave * 1024;

  // preload K frags for first iteration
  s16x8 ka[8];
  {
    const unsigned short* kr0 = Kb + (size_t)(kb0 + l15) * HN + quad * 8;
#pragma unroll
    for (int t = 0; t < 4; ++t) {
      ka[2 * t] = *(const s16x8*)(kr0 + (size_t)t * 16 * HN);
      ka[2 * t + 1] = *(const s16x8*)(kr0 + (size_t)t * 16 * HN + 32);
    }
  }

  f32x4 o[4];
#pragma unroll
  for (int t = 0; t < 4; ++t) o[t] = 0.f;
  float lacc = 0.f;

  for (int it = 0; it < 16; ++it) {
    const int kb = kb0 + it * 64;
    // ---- S^T = K-tile * Q^T (consumes ka: loaded a full iteration ago) ----
    f32x4 s[4];
#pragma unroll
    for (int t = 0; t < 4; ++t) {
      s[t] = 0.f;
      s[t] = __builtin_amdgcn_mfma_f32_16x16x32_bf16(ka[2 * t], qf0, s[t], 0, 0, 0);
      s[t] = __builtin_amdgcn_mfma_f32_16x16x32_bf16(ka[2 * t + 1], qf1, s[t], 0, 0, 0);
    }
    // ---- prefetch next-iter K frags (land during exp + next S issue) ----
    const int kbn = kb0 + ((it + 1) & 15) * 64;  // wraps on last iter (harmless)
    s16x8 kn[8];
    {
      const unsigned short* krn = Kb + (size_t)(kbn + l15) * HN + quad * 8;
#pragma unroll
      for (int t = 0; t < 4; ++t) {
        kn[2 * t] = *(const s16x8*)(krn + (size_t)t * 16 * HN);
        kn[2 * t + 1] = *(const s16x8*)(krn + (size_t)t * 16 * HN + 32);
      }
    }
    // ---- this-iter V frags (covered by the exp2/pack stretch below) ----
    s16x8 va[8];
#pragma unroll
    for (int kc = 0; kc < 2; ++kc)
#pragma unroll
      for (int ht = 0; ht < 4; ++ht)
        va[kc * 4 + ht] = *(const s16x8*)(Vb + (size_t)(ht * 16 + l15) * TN +
                                          kb + kc * 32 + quad * 8);
    // ---- exp2, truncate to bf16, l from truncated values, store P^T ----
    // S^T C/D layout: q=l15(col), key = 16t + quad*4 + reg
#pragma unroll
    for (int t = 0; t < 4; ++t) {
      unsigned int u0 = __float_as_uint(fast_exp2(fminf(s[t][0], 80.f)));
      unsigned int u1 = __float_as_uint(fast_exp2(fminf(s[t][1], 80.f)));
      unsigned int u2 = __float_as_uint(fast_exp2(fminf(s[t][2], 80.f)));
      unsigned int u3 = __float_as_uint(fast_exp2(fminf(s[t][3], 80.f)));
      u0 &= 0xffff0000u; u1 &= 0xffff0000u;
      u2 &= 0xffff0000u; u3 &= 0xffff0000u;
      lacc += (__uint_as_float(u0) + __uint_as_float(u1)) +
              (__uint_as_float(u2) + __uint_as_float(u3));
      u32x2 w;
      w.x = (u0 >> 16) | u1;
      w.y = (u2 >> 16) | u3;
      *(u32x2*)(pw + t * 32 + quad * 8) = w;  // keys 16t+quad*4 .. +3
    }
    // ---- O^T += Vt * P^T (same-wave LDS RAW; V landed during exp) ----
#pragma unroll
    for (int kc = 0; kc < 2; ++kc) {
      const s16x8 pb = *(const s16x8*)(pr + kc * 64);
#pragma unroll
      for (int ht = 0; ht < 4; ++ht)
        o[ht] = __builtin_amdgcn_mfma_f32_16x16x32_bf16(va[kc * 4 + ht], pb,
                                                        o[ht], 0, 0, 0);
    }
    // rotate K pipeline
#pragma unroll
    for (int j = 0; j < 8; ++j) ka[j] = kn[j];
  }
  // l currently partial per lane (its own keys); reduce across quads
  lacc += __shfl_xor(lacc, 16, 64);
  lacc += __shfl_xor(lacc, 32, 64);
  __syncthreads();  // all waves done with sm.p before union reuse
  if (lane < 16) sm.m.lb[wave][l15] = lacc;
#pragma unroll
  for (int ht = 0; ht < 4; ++ht)
#pragma unroll
    for (int r = 0; r < 4; ++r)
      sm.m.ob[wave][ht * 16 + quad * 4 + r][l15] = o[ht][r];
  __syncthreads();
  // merge 4 key-split partials, normalize, coalesced store
  const int h = tid & 63;
#pragma unroll
  for (int i = 0; i < 4; ++i) {
    const int qq = (i << 2) | (tid >> 6);
    const float ssum = sm.m.ob[0][h][qq] + sm.m.ob[1][h][qq] +
                       sm.m.ob[2][h][qq] + sm.m.ob[3][h][qq];
    const float ll = sm.m.lb[0][qq] + sm.m.lb[1][qq] +
                     sm.m.lb[2][qq] + sm.m.lb[3][qq];
    out[(size_t)(b * TN + qbase + qq) * HN + h] = ssum / ll;
  }
}

extern "C" void kernel_launch(void* const* d_in, const int* in_sizes, int n_in,
                              void* d_out, int out_size, void* d_ws,
                              size_t ws_size, hipStream_t stream) {
  const float* x = (const float*)d_in[0];
  const float* Wk = (const float*)d_in[1];
  const float* Wq = (const float*)d_in[2];
  const float* Wv = (const float*)d_in[3];
  unsigned short* Kg = (unsigned short*)d_ws;             // [B*T][64] bf16
  unsigned short* Qg = Kg + (size_t)BN * TN * HN;         // [B*T][64] bf16
  unsigned short* Vt = Qg + (size_t)BN * TN * HN;         // [B][64][T] bf16
  float* out = (float*)d_out;
  proj_kernel<<<BN * TN / 16, 256, 0, stream>>>(x, Wk, Wq, Wv, Kg, Qg, Vt);
  attn_kernel<<<BN * TN / 16, 256, 0, stream>>>(Qg, Kg, Vt, out);
}

// Round 8
// 201.716 us; speedup vs baseline: 1.1062x; 1.1062x over previous
//
#include <hip/hip_runtime.h>

typedef __attribute__((ext_vector_type(2))) float f32x2;
typedef __attribute__((ext_vector_type(4))) float f32x4;
typedef __attribute__((ext_vector_type(8))) short s16x8;
typedef __attribute__((ext_vector_type(2))) unsigned int u32x2;
typedef __attribute__((ext_vector_type(4))) unsigned int u32x4;

#define BN 4
#define TN 4096
#define CN 120
#define HN 64

// RNE float->bf16 (finite inputs only)
__device__ __forceinline__ unsigned short f2bf(float f) {
  unsigned int u = __float_as_uint(f);
  unsigned int r = (u + 0x7fffu + ((u >> 16) & 1u)) >> 16;
  return (unsigned short)r;
}
__device__ __forceinline__ float fast_exp2(float x) {
#if __has_builtin(__builtin_amdgcn_exp2f)
  return __builtin_amdgcn_exp2f(x);
#else
  return exp2f(x);
#endif
}

// ---------------------------------------------------------------------------
// Kernel 1: projections, one matrix per block (grid 768 = 256 rowblocks x 3).
// W fp32 (30.7KB) + 64 x rows fp32 (31.7KB) in LDS -> 61KB, 2 blocks/CU;
// inner loop pure LDS+FMA. Numerically identical to round-1's verified proj
// (fp32 W, fp32 accum, RNE bf16 outputs).
//   Kg [b*T+t][64] bf16 rows; Qg same, pre-scaled by log2(e)/sqrt(C);
//   Vt [b][h][t] bf16 (transposed for attention's PV A-operand).
// ---------------------------------------------------------------------------
__global__ __launch_bounds__(256, 2) void proj_kernel(
    const float* __restrict__ x, const float* __restrict__ Wk,
    const float* __restrict__ Wq, const float* __restrict__ Wv,
    unsigned short* __restrict__ Kg, unsigned short* __restrict__ Qg,
    unsigned short* __restrict__ Vt) {
  __shared__ struct {
    float w[CN][HN];              // fp32 W for this block's mat     30720 B
    union {
      float xr[64][124];          // fp32 x rows (pitch 124)         31744 B
      unsigned short vt[64][72];  // V transpose buffer               9216 B
    } u;
  } sm;
  const int tid = threadIdx.x;
  const int mat = blockIdx.x >> 8;  // 0=K 1=Q 2=V
  const int rb = blockIdx.x & 255;
  const int row0 = rb * 64;
  const float* Ws = (mat == 0) ? Wk : (mat == 1) ? Wq : Wv;
  {  // stage W fp32, coalesced f32x4
    const f32x4* s = (const f32x4*)Ws;
    f32x4* d = (f32x4*)&sm.w[0][0];
    for (int i = tid; i < CN * HN / 4; i += 256) d[i] = s[i];
  }
  // stage x fp32 (row pitch 124 floats)
  for (int n = tid; n < 64 * 30; n += 256) {
    const int row = n / 30, c4 = n - row * 30;
    *(f32x4*)&sm.u.xr[row][c4 * 4] =
        *(const f32x4*)&x[(size_t)(row0 + row) * CN + c4 * 4];
  }
  __syncthreads();
  const int hg = tid & 15;  // h = hg*4 .. +3
  const int rg = tid >> 4;  // rows rg*4 .. +3
  f32x4 acc[4];
#pragma unroll
  for (int r = 0; r < 4; ++r) acc[r] = 0.f;
  for (int c = 0; c < CN; c += 4) {
    f32x4 xv[4];
#pragma unroll
    for (int r = 0; r < 4; ++r) xv[r] = *(const f32x4*)&sm.u.xr[rg * 4 + r][c];
#pragma unroll
    for (int cc = 0; cc < 4; ++cc) {
      const f32x4 wv = *(const f32x4*)&sm.w[c + cc][hg * 4];
#pragma unroll
      for (int r = 0; r < 4; ++r) acc[r] += wv * xv[r][cc];
    }
  }
  if (mat < 2) {
    // K rows plain; Q rows pre-scaled by log2(e)/sqrt(120) (folds softmax
    // scale AND exp->exp2 into Q)
    const float sc = (mat == 1) ? 0.13169944f : 1.0f;
    unsigned short* dst = (mat == 1) ? Qg : Kg;
#pragma unroll
    for (int r = 0; r < 4; ++r) {
      u32x2 wd;
      wd.x = (unsigned int)f2bf(acc[r][0] * sc) |
             ((unsigned int)f2bf(acc[r][1] * sc) << 16);
      wd.y = (unsigned int)f2bf(acc[r][2] * sc) |
             ((unsigned int)f2bf(acc[r][3] * sc) << 16);
      *(u32x2*)&dst[(size_t)(row0 + rg * 4 + r) * HN + hg * 4] = wd;
    }
  } else {
    // V: transpose through LDS, then coalesced 16B global writes
    __syncthreads();  // xr no longer needed (union reuse)
#pragma unroll
    for (int r = 0; r < 4; ++r)
#pragma unroll
      for (int j = 0; j < 4; ++j)
        sm.u.vt[hg * 4 + j][rg * 4 + r] = f2bf(acc[r][j]);
    __syncthreads();
    const int h = tid >> 2, ck = tid & 3;
    const int b = row0 >> 12, key0 = row0 & (TN - 1);
    unsigned short* vrow = Vt + (size_t)(b * HN + h) * TN + key0 + ck * 16;
    const u32x4 d0 = *(const u32x4*)&sm.u.vt[h][ck * 16];
    const u32x4 d1 = *(const u32x4*)&sm.u.vt[h][ck * 16 + 8];
    *(u32x4*)vrow = d0;
    *(u32x4*)(vrow + 8) = d1;
  }
}

// ---------------------------------------------------------------------------
// Kernel 2: attention — ROUND-1-VERIFIED math (passed at 1.95e-3), widened
// from 4 to 8 waves per 16q block for TLP (round-1 bottleneck: Occupancy 40%
// vs ~600cy serial load chain; compiler sinks register prefetches, VGPR=52
// proved it in round 3).
// Round-7 hedge vs "container failed twice": launch_bounds (512,8)->(512,4)
// (no forced 64-VGPR cap -> no pathological spill path; expected natural
// VGPR ~52 still gives 8 waves/EU, and LDS 35.3KB caps at 4 blocks/CU = 32
// waves/CU either way) + #pragma unroll 1 on the key loop (forbid register-
// exploding unrolls). Math byte-identical to round 1.
// ---------------------------------------------------------------------------
__global__ __launch_bounds__(512, 4) void attn_kernel(
    const unsigned short* __restrict__ Qg, const unsigned short* __restrict__ Kg,
    const unsigned short* __restrict__ Vt, float* __restrict__ out) {
  __shared__ union {
    unsigned short p[8][16][72];                         // 18432 B
    struct { float ob[8][64][17]; float lb[8][16]; } m;  // 35328 B
  } sm;
  const int bid = blockIdx.x;
  const int xslot = bid & 7;                 // XCD-aware swizzle:
  const int b = xslot >> 1;                  // batch pinned to an XCD pair
  const int qt = (bid >> 3) | ((xslot & 1) << 7);  // [0,256)
  const int qbase = qt * 16;
  const int tid = threadIdx.x;
  const int wave = tid >> 6, lane = tid & 63;
  const int l15 = lane & 15, quad = lane >> 4;

  // Q B-operand frags: B[k=h][n=q]: q = lane&15, h = quad*8+j (+32)
  const unsigned short* qrow =
      Qg + (size_t)(b * TN + qbase + l15) * HN + quad * 8;
  const s16x8 qf0 = *(const s16x8*)qrow;
  const s16x8 qf1 = *(const s16x8*)(qrow + 32);

  const unsigned short* Kb = Kg + (size_t)b * TN * HN;
  const unsigned short* Vb = Vt + (size_t)b * HN * TN;
  char* const pw = (char*)&sm.p[wave][0][0] + l15 * 144;  // write row q=l15
  char* const pr = (char*)&sm.p[wave][0][0] + l15 * 144 + quad * 16;

  f32x4 o[4];
#pragma unroll
  for (int t = 0; t < 4; ++t) o[t] = 0.f;
  float lacc = 0.f;

  const int kb0 = wave * 512;  // 8-way key split, 512 keys/wave
#pragma unroll 1
  for (int it = 0; it < 8; ++it) {
    const int kb = kb0 + it * 64;
    // ---- S^T = K-tile * Q^T ----
    f32x4 s[4];
#pragma unroll
    for (int t = 0; t < 4; ++t) {
      // A-operand: A[m=key16][k=h]: key row = kb+16t+l15, h = quad*8+j
      const unsigned short* kr =
          Kb + (size_t)(kb + t * 16 + l15) * HN + quad * 8;
      const s16x8 a0 = *(const s16x8*)kr;
      const s16x8 a1 = *(const s16x8*)(kr + 32);
      s[t] = 0.f;
      s[t] = __builtin_amdgcn_mfma_f32_16x16x32_bf16(a0, qf0, s[t], 0, 0, 0);
      s[t] = __builtin_amdgcn_mfma_f32_16x16x32_bf16(a1, qf1, s[t], 0, 0, 0);
    }
    // ---- exp2, truncate to bf16, l from truncated values, store P^T ----
    // S^T C/D layout: q=l15(col), key = 16t + quad*4 + reg
#pragma unroll
    for (int t = 0; t < 4; ++t) {
      unsigned int u0 = __float_as_uint(fast_exp2(fminf(s[t][0], 80.f)));
      unsigned int u1 = __float_as_uint(fast_exp2(fminf(s[t][1], 80.f)));
      unsigned int u2 = __float_as_uint(fast_exp2(fminf(s[t][2], 80.f)));
      unsigned int u3 = __float_as_uint(fast_exp2(fminf(s[t][3], 80.f)));
      u0 &= 0xffff0000u; u1 &= 0xffff0000u;
      u2 &= 0xffff0000u; u3 &= 0xffff0000u;
      lacc += (__uint_as_float(u0) + __uint_as_float(u1)) +
              (__uint_as_float(u2) + __uint_as_float(u3));
      u32x2 w;
      w.x = (u0 >> 16) | u1;
      w.y = (u2 >> 16) | u3;
      *(u32x2*)(pw + t * 32 + quad * 8) = w;  // keys 16t+quad*4 .. +3
    }
    // ---- O^T += Vt * P^T (same-wave LDS RAW: DS ops complete in order) ----
#pragma unroll
    for (int kc = 0; kc < 2; ++kc) {
      // B-operand: B[k=key][n=q]: row q=l15, key bytes quad*16 + kc*64
      const s16x8 pb = *(const s16x8*)(pr + kc * 64);
#pragma unroll
      for (int ht = 0; ht < 4; ++ht) {
        // A-operand: A[m=h16][k=key]: Vt row h=16ht+l15, key = kb+32kc+quad*8+j
        const unsigned short* vr =
            Vb + (size_t)(ht * 16 + l15) * TN + kb + kc * 32 + quad * 8;
        const s16x8 va = *(const s16x8*)vr;
        o[ht] = __builtin_amdgcn_mfma_f32_16x16x32_bf16(va, pb, o[ht], 0, 0, 0);
      }
    }
  }
  // l currently partial per lane (its own keys); reduce across quads
  lacc += __shfl_xor(lacc, 16, 64);
  lacc += __shfl_xor(lacc, 32, 64);
  __syncthreads();  // all waves done with sm.p before union reuse
  if (lane < 16) sm.m.lb[wave][l15] = lacc;
#pragma unroll
  for (int ht = 0; ht < 4; ++ht)
#pragma unroll
    for (int r = 0; r < 4; ++r)
      sm.m.ob[wave][ht * 16 + quad * 4 + r][l15] = o[ht][r];
  __syncthreads();
  // merge 8 key-split partials, normalize, coalesced store
  const int h = tid & 63;
  const int wq = tid >> 6;  // 0..7
#pragma unroll
  for (int i = 0; i < 2; ++i) {
    const int qq = (i << 3) | wq;  // 0..15
    float ssum = 0.f, ll = 0.f;
#pragma unroll
    for (int w = 0; w < 8; ++w) {
      ssum += sm.m.ob[w][h][qq];
      ll += sm.m.lb[w][qq];
    }
    out[(size_t)(b * TN + qbase + qq) * HN + h] = ssum / ll;
  }
}

extern "C" void kernel_launch(void* const* d_in, const int* in_sizes, int n_in,
                              void* d_out, int out_size, void* d_ws,
                              size_t ws_size, hipStream_t stream) {
  const float* x = (const float*)d_in[0];
  const float* Wk = (const float*)d_in[1];
  const float* Wq = (const float*)d_in[2];
  const float* Wv = (const float*)d_in[3];
  unsigned short* Kg = (unsigned short*)d_ws;             // [B*T][64] bf16
  unsigned short* Qg = Kg + (size_t)BN * TN * HN;         // [B*T][64] bf16
  unsigned short* Vt = Qg + (size_t)BN * TN * HN;         // [B][64][T] bf16
  float* out = (float*)d_out;
  proj_kernel<<<768, 256, 0, stream>>>(x, Wk, Wq, Wv, Kg, Qg, Vt);
  attn_kernel<<<BN * TN / 16, 512, 0, stream>>>(Qg, Kg, Vt, out);  // 1024
}